// Round 8
// baseline (232.590 us; speedup 1.0000x reference)
//
#include <hip/hip_runtime.h>
#include <hip/hip_bf16.h>
#include <cstdint>
#include <cstddef>

// Problem constants (fixed by reference)
#define BB 32
#define NN 8192
#define DIN 64
#define DOUT 128
#define NR 4
#define BN_EPS 1e-5f
#define NCHUNK 32  // n-chunks per batch in k_compute (NN/256)

typedef float nfloat4 __attribute__((ext_vector_type(4)));
typedef float floatx4 __attribute__((ext_vector_type(4)));
typedef short short8 __attribute__((ext_vector_type(8)));

// Workspace: partials[b][r][chan][nchunk] float, 32*4*128*32*4B = 2 MB.
// Every slot is written unconditionally by k_compute each launch, so the
// harness's 0xAA poison needs no memset. No atomics, no init dispatch.

__device__ inline void pack2(float a, float b, short8& dst, int idx) {
  // packed f32x2 -> bf16x2 (v_cvt_pk_bf16_f32 on gfx950)
  __hip_bfloat162 h = __float22bfloat162_rn(make_float2(a, b));
  const unsigned int bits = *(unsigned int*)&h;
  dst[idx] = (short)(bits & 0xffffu);
  dst[idx + 1] = (short)(bits >> 16);
}

// ---------------------------------------------------------------------------
// K1 (MFMA, no bucketing): block = (b, 256-point chunk). Wave w owns channel
// tiles {w, w+4} (32 chans). B-fragments load DIRECTLY from x's native [d][n]
// layout: lane(l16,quad) reads x[quad*8+j][n0+T*16+l16] -- each 16-lane group
// covers 16 consecutive n = full 64B lines, so x is fetched exactly once,
// fully coalesced. Each point only contributes through its own ring's W, but
// an MFMA tile mixes rings, so we run the tile against all NR weight sets and
// mask per-ring with (ring==r ? v : -inf). 4x MFMA is still only ~2 us.
// Per-block result goes to a PRIVATE partials slot (plain stores, no atomics).
__global__ void __launch_bounds__(256) k_compute(
    const float* __restrict__ x, const float* __restrict__ W,
    const int* __restrict__ ring, float* __restrict__ partials) {
  const int b = blockIdx.y;
  const int nchunk = blockIdx.x;
  const int n0 = nchunk * 256;
  const int wave = (int)threadIdx.x >> 6;
  const int lane = (int)threadIdx.x & 63;
  const int quad = lane >> 4;
  const int l16 = lane & 15;
  const float* xb = x + (size_t)b * DIN * NN;
  const int* rgb = ring + (size_t)b * NN;

  // A fragments for all NR rings: afr[r][tt][kstep], chan-tile t = wave+4*tt,
  // A[m=l16][k=quad*8+j]. 4*2*2*4 = 64 VGPR of bf16 A data, loaded once.
  short8 afr[NR][2][2];
#pragma unroll
  for (int r = 0; r < NR; ++r) {
#pragma unroll
    for (int tt = 0; tt < 2; ++tt) {
      const int chan = (wave + 4 * tt) * 16 + l16;
      const float* wr = W + ((size_t)r * DOUT + chan) * DIN + quad * 8;
#pragma unroll
      for (int ks = 0; ks < 2; ++ks) {
        const float4 w0 = *(const float4*)&wr[ks * 32];
        const float4 w1 = *(const float4*)&wr[ks * 32 + 4];
        short8 a;
        pack2(w0.x, w0.y, a, 0);
        pack2(w0.z, w0.w, a, 2);
        pack2(w1.x, w1.y, a, 4);
        pack2(w1.z, w1.w, a, 6);
        afr[r][tt][ks] = a;
      }
    }
  }

  floatx4 rmax[2][NR];
#pragma unroll
  for (int tt = 0; tt < 2; ++tt)
#pragma unroll
    for (int r = 0; r < NR; ++r)
      rmax[tt][r] = {-INFINITY, -INFINITY, -INFINITY, -INFINITY};

#pragma unroll 1
  for (int T = 0; T < 16; ++T) {
    const int n = n0 + T * 16 + l16;
    const int rr = rgb[n];
    // B fragments from native layout: b0 k=quad*8+j, b1 k=32+quad*8+j
    float bx[8], by[8];
#pragma unroll
    for (int j = 0; j < 8; ++j) {
      bx[j] = xb[(size_t)(quad * 8 + j) * NN + n];
      by[j] = xb[(size_t)(32 + quad * 8 + j) * NN + n];
    }
    short8 b0, b1;
#pragma unroll
    for (int j = 0; j < 4; ++j) {
      pack2(bx[2 * j], bx[2 * j + 1], b0, 2 * j);
      pack2(by[2 * j], by[2 * j + 1], b1, 2 * j);
    }
#pragma unroll
    for (int r = 0; r < NR; ++r) {
      floatx4 acc0 = {0.f, 0.f, 0.f, 0.f};
      floatx4 acc1 = {0.f, 0.f, 0.f, 0.f};
      acc0 = __builtin_amdgcn_mfma_f32_16x16x32_bf16(afr[r][0][0], b0, acc0, 0, 0, 0);
      acc0 = __builtin_amdgcn_mfma_f32_16x16x32_bf16(afr[r][0][1], b1, acc0, 0, 0, 0);
      acc1 = __builtin_amdgcn_mfma_f32_16x16x32_bf16(afr[r][1][0], b0, acc1, 0, 0, 0);
      acc1 = __builtin_amdgcn_mfma_f32_16x16x32_bf16(afr[r][1][1], b1, acc1, 0, 0, 0);
      const bool m = (rr == r);
#pragma unroll
      for (int p = 0; p < 4; ++p) {
        rmax[0][r][p] = fmaxf(rmax[0][r][p], m ? acc0[p] : -INFINITY);
        rmax[1][r][p] = fmaxf(rmax[1][r][p], m ? acc1[p] : -INFINITY);
      }
    }
  }

  // reduce over the 16 point-columns (lane bits 0-3); one plain store per
  // (ring, chan) into this block's private partial slot.
#pragma unroll
  for (int tt = 0; tt < 2; ++tt) {
#pragma unroll
    for (int r = 0; r < NR; ++r) {
#pragma unroll
      for (int p = 0; p < 4; ++p) {
        float v = rmax[tt][r][p];
        v = fmaxf(v, __shfl_xor(v, 1, 64));
        v = fmaxf(v, __shfl_xor(v, 2, 64));
        v = fmaxf(v, __shfl_xor(v, 4, 64));
        v = fmaxf(v, __shfl_xor(v, 8, 64));
        if (l16 == 0) {
          const int chan = (wave + 4 * tt) * 16 + quad * 4 + p;
          partials[(((size_t)(b * NR + r)) * DOUT + chan) * NCHUNK + nchunk] = v;
        }
      }
    }
  }
}

// ---------------------------------------------------------------------------
// K2: phase 1 reduces the 32 per-chunk partials (float4 loads, L2-resident)
// and applies the BN affine; phase 2 broadcasts to the output:
// out[b][o][n] = ymax[b][ring[b,n]][o]. Nontemporal float4 stores along n.
// LDS table [oo][r] so the 4 ring values sit in 4 different banks.
__global__ void k_out(const float* __restrict__ bias, const float* __restrict__ gamma,
                      const float* __restrict__ beta, const float* __restrict__ mean,
                      const float* __restrict__ var, const int* __restrict__ ring,
                      const float* __restrict__ partials, float* __restrict__ out) {
  const int b = blockIdx.z;
  const int og = blockIdx.y;  // 32-channel group
  const int n0 = blockIdx.x * 1024;

  __shared__ float ymax[32 * NR];  // [oo][r]
  if (threadIdx.x < 32 * NR) {
    const int oo = (int)threadIdx.x >> 2;
    const int r = (int)threadIdx.x & 3;
    const int o = og * 32 + oo;
    const int t = r * DOUT + o;
    const float* ps = partials + (((size_t)b * NR + r) * DOUT + o) * NCHUNK;
    float raw = -INFINITY;
#pragma unroll
    for (int j = 0; j < NCHUNK / 4; ++j) {
      const nfloat4 v = *(const nfloat4*)&ps[4 * j];
      raw = fmaxf(raw, fmaxf(fmaxf(v.x, v.y), fmaxf(v.z, v.w)));
    }
    const float sc = gamma[t] * rsqrtf(var[t] + BN_EPS);
    ymax[oo * NR + r] = (raw + bias[t] - mean[t]) * sc + beta[t];
  }
  __syncthreads();

  const int n = n0 + (int)threadIdx.x * 4;
  const int4 rg = *(const int4*)&ring[(size_t)b * NN + n];
#pragma unroll 8
  for (int oo = 0; oo < 32; ++oo) {
    const int o = og * 32 + oo;
    nfloat4 v;
    v.x = ymax[oo * NR + rg.x];
    v.y = ymax[oo * NR + rg.y];
    v.z = ymax[oo * NR + rg.z];
    v.w = ymax[oo * NR + rg.w];
    __builtin_nontemporal_store(v, (nfloat4*)&out[((size_t)b * DOUT + o) * NN + n]);
  }
}

// ---------------------------------------------------------------------------
extern "C" void kernel_launch(void* const* d_in, const int* in_sizes, int n_in,
                              void* d_out, int out_size, void* d_ws, size_t ws_size,
                              hipStream_t stream) {
  const float* x = (const float*)d_in[0];
  const int* ring = (const int*)d_in[1];
  const float* W = (const float*)d_in[2];
  const float* bias = (const float*)d_in[3];
  const float* gamma = (const float*)d_in[4];
  const float* beta = (const float*)d_in[5];
  const float* mean = (const float*)d_in[6];
  const float* var = (const float*)d_in[7];
  float* out = (float*)d_out;

  float* partials = (float*)d_ws;  // 2 MB, fully rewritten every launch

  k_compute<<<dim3(NCHUNK, BB), 256, 0, stream>>>(x, W, ring, partials);
  k_out<<<dim3(NN / 1024, DOUT / 32, BB), 256, 0, stream>>>(bias, gamma, beta, mean,
                                                            var, ring, partials, out);
}